// Round 7
// baseline (335.930 us; speedup 1.0000x reference)
//
#include <hip/hip_runtime.h>
#include <math.h>

// Problem constants (fixed by setup_inputs)
#define BN   32      // batch
#define NN   300     // num preds (columns of the transposed k x 300 problem)
#define MM   60      // max targets (rows)
#define LAUX 5       // aux layers
#define CNUM 1000    // classes

#define LC_ROWS 54   // cost rows staged in LDS (54*300*4 + pad <= 64 KiB)
#define REX_ROWS 6   // rows 54..59 live in wave0 registers
#define CINF 3.0e38f

// Accumulator slots
#define ACC_CLS   0
#define ACC_OBJ   1
#define ACC_AOBJ  2
#define ACC_BBOX  3
#define ACC_GIOU  4
#define ACC_ABBOX 5
#define ACC_AGIOU 6
#define ACC_NB    7

#define PAIR_BLOCKS ((BN * NN + 255) / 256)   // 38
#define GRID_L (PAIR_BLOCKS + BN)             // 70

__device__ int    g_match[BN * NN];
__device__ double g_acc[8];
__device__ int    g_done;

__device__ __forceinline__ float giou_box(float ax0, float ay0, float ax1, float ay1,
                                          float bx0, float by0, float bx1, float by1) {
    const float EPS = 1e-7f;
    float area_a = (ax1 - ax0) * (ay1 - ay0);
    float area_b = (bx1 - bx0) * (by1 - by0);
    float ltx = fmaxf(ax0, bx0), lty = fmaxf(ay0, by0);
    float rbx = fminf(ax1, bx1), rby = fminf(ay1, by1);
    float w = fmaxf(rbx - ltx, 0.0f), h = fmaxf(rby - lty, 0.0f);
    float inter = w * h;
    float uni = area_a + area_b - inter;
    float iou = inter / (uni + EPS);
    float ex0 = fminf(ax0, bx0), ey0 = fminf(ay0, by0);
    float ex1 = fmaxf(ax1, bx1), ey1 = fmaxf(ay1, by1);
    float ew = fmaxf(ex1 - ex0, 0.0f), eh = fmaxf(ey1 - ey0, 0.0f);
    float enc = ew * eh;
    return iou - (enc - uni) / (enc + EPS);
}

// cost(pred box p, tgt box t) = 5*L1 - 2*giou  (f32, same op order as reference)
__device__ __forceinline__ float cost_pt(float4 p, float4 t) {
    float l1 = fabsf(p.x - t.x) + fabsf(p.y - t.y) + fabsf(p.z - t.z) + fabsf(p.w - t.w);
    float gi = giou_box(p.x - p.z * 0.5f, p.y - p.w * 0.5f, p.x + p.z * 0.5f, p.y + p.w * 0.5f,
                        t.x - t.z * 0.5f, t.y - t.w * 0.5f, t.x + t.z * 0.5f, t.y + t.w * 0.5f);
    return 5.0f * l1 - 2.0f * gi;
}

// ---- packed-key wave argmin ------------------------------------------------
// key = order-preserving f32 (upper 23 bits) | column (low 9 bits); floor quant.
__device__ __forceinline__ unsigned enc_key(float x, int col) {
    unsigned u = __float_as_uint(x);
    unsigned e = (u & 0x80000000u) ? ~u : (u | 0x80000000u);
    return (e & 0xFFFFFE00u) | (unsigned)col;
}
__device__ __forceinline__ float dec_key(unsigned kk) {
    unsigned e = kk & 0xFFFFFE00u;
    unsigned u = (e & 0x80000000u) ? (e & 0x7FFFFFFFu) : ~e;
    return __uint_as_float(u);
}

__device__ __forceinline__ unsigned wave_min_u32(unsigned k) {
#define WSTEP(C) { unsigned t = (unsigned)__builtin_amdgcn_update_dpp((int)k, (int)k, (C), 0xF, 0xF, false); \
                   k = (t < k) ? t : k; }
    WSTEP(0x111) WSTEP(0x112) WSTEP(0x114) WSTEP(0x118) WSTEP(0x142) WSTEP(0x143)
#undef WSTEP
    return (unsigned)__builtin_amdgcn_readlane((int)k, 63);
}

__device__ __forceinline__ int sel5i(const int* a, int s) {
    int r = a[0];
    r = (s == 1) ? a[1] : r;
    r = (s == 2) ? a[2] : r;
    r = (s == 3) ? a[3] : r;
    r = (s == 4) ? a[4] : r;
    return r;
}
__device__ __forceinline__ float sel5f(const float* a, int s) {
    float r = a[0];
    r = (s == 1) ? a[1] : r;
    r = (s == 2) ? a[2] : r;
    r = (s == 3) ? a[3] : r;
    r = (s == 4) ? a[4] : r;
    return r;
}
__device__ __forceinline__ int rdlane_i(int x, int l) { return __builtin_amdgcn_readlane(x, l); }
__device__ __forceinline__ float rdlane_f(float x, int l) {
    return __uint_as_float((unsigned)__builtin_amdgcn_readlane(__float_as_int(x), l));
}

// ---- fused cost + JV solver (R3-validated greedy + Dijkstra) ---------------
// Rectangular-LAP optimality invariant (the R4-R6 bug): duals must keep
// v <= 0 everywhere and v == 0 on every UNASSIGNED column. So: NO column
// reduction. v starts 0 and is only decreased on assigned (used) columns by
// the Dijkstra dual updates, exactly like the reference numpy JV.
// Greedy: u[r] = raw row min, assign at raw argmin column if free (tight+feasible).
__global__ __launch_bounds__(128) void hung_kernel(const float* __restrict__ pred,
                                                   const float* __restrict__ tgt,
                                                   const float* __restrict__ mask) {
    const int b = blockIdx.x;
    const int tid = threadIdx.x;
    const int lane = tid & 63;
    const int wid = tid >> 6;

    __shared__ float lc[LC_ROWS * NN + 32];

    if (b == 0 && tid == 0) {
        __hip_atomic_store(&g_done, 0, __ATOMIC_RELAXED, __HIP_MEMORY_SCOPE_AGENT);
#pragma unroll
        for (int i = 0; i < 8; i++)
            __hip_atomic_store(&g_acc[i], 0.0, __ATOMIC_RELAXED, __HIP_MEMORY_SCOPE_AGENT);
    }

    float mval = (lane < MM) ? mask[b * MM + lane] : 0.0f;
    int k = __popcll(__ballot(mval > 0.5f));

    // per-lane pred boxes for its 5 columns
    float4 pb[5];
#pragma unroll
    for (int s = 0; s < 5; s++) {
        int c = s * 64 + lane;
        pb[s] = (c < NN) ? ((const float4*)pred)[b * NN + c]
                         : make_float4(0.f, 0.f, 0.f, 0.f);
    }

    float rex[REX_ROWS][5];

    int kl = (k < LC_ROWS) ? k : LC_ROWS;
    for (int r = wid; r < kl; r += 2) {
        float4 tb = ((const float4*)tgt)[b * MM + r];
#pragma unroll
        for (int s = 0; s < 5; s++) {
            int c = s * 64 + lane;
            if (c < NN) lc[r * NN + c] = cost_pt(pb[s], tb);
        }
    }
    if (wid == 0) {
        for (int r = LC_ROWS; r < k; r++) {
            float4 tb = ((const float4*)tgt)[b * MM + r];
#pragma unroll
            for (int s = 0; s < 5; s++) rex[r - LC_ROWS][s] = cost_pt(pb[s], tb);
        }
    }
    __syncthreads();
    if (wid == 1) return;

#define LOAD_ROW(ROW, RV) do {                                                  \
    int _r = (ROW);                                                             \
    if (_r < LC_ROWS) {                                                         \
        _Pragma("unroll")                                                       \
        for (int _s = 0; _s < 5; _s++) RV[_s] = lc[_r * NN + _s * 64 + lane];   \
    } else {                                                                    \
        switch (_r - LC_ROWS) {                                                 \
        case 0: _Pragma("unroll") for (int _s = 0; _s < 5; _s++) RV[_s] = rex[0][_s]; break; \
        case 1: _Pragma("unroll") for (int _s = 0; _s < 5; _s++) RV[_s] = rex[1][_s]; break; \
        case 2: _Pragma("unroll") for (int _s = 0; _s < 5; _s++) RV[_s] = rex[2][_s]; break; \
        case 3: _Pragma("unroll") for (int _s = 0; _s < 5; _s++) RV[_s] = rex[3][_s]; break; \
        case 4: _Pragma("unroll") for (int _s = 0; _s < 5; _s++) RV[_s] = rex[4][_s]; break; \
        default: _Pragma("unroll") for (int _s = 0; _s < 5; _s++) RV[_s] = rex[5][_s]; break; \
        }                                                                       \
    }                                                                           \
} while (0)

    int used_inv = 0;
#pragma unroll
    for (int s = 0; s < 5; s++)
        if (s * 64 + lane >= NN) used_inv |= 1 << s;

    float v[5], uc[5], minv[5];
    int pc[5], way[5];
#pragma unroll
    for (int s = 0; s < 5; s++) { v[s] = 0.0f; uc[s] = 0.0f; pc[s] = 0; way[s] = 0; }

    // ---- greedy (R3-validated): u[r] = raw row min; assign argmin col if free ----
    unsigned long long freeM = 0ull;
    for (int r = 0; r < k; r++) {
        float rv[5];
        LOAD_ROW(r, rv);
        unsigned kbest = 0xFFFFFFFFu;
#pragma unroll
        for (int s = 0; s < 5; s++) {
            if (!((used_inv >> s) & 1)) {
                unsigned kk = enc_key(rv[s], s * 64 + lane);
                kbest = (kk < kbest) ? kk : kbest;
            }
        }
        unsigned kmin = wave_min_u32(kbest);
        float umin = dec_key(kmin);            // floor-quant row min (<= true => feasible)
        int jcol = (int)(kmin & 0x1FFu);
        int sl = jcol >> 6, ow = jcol & 63;
        int pj = rdlane_i(sel5i(pc, sl), ow);
        if (pj == 0) {
            if (lane == ow) {
                if      (sl == 0) { pc[0] = r + 1; uc[0] = umin; }
                else if (sl == 1) { pc[1] = r + 1; uc[1] = umin; }
                else if (sl == 2) { pc[2] = r + 1; uc[2] = umin; }
                else if (sl == 3) { pc[3] = r + 1; uc[3] = umin; }
                else              { pc[4] = r + 1; uc[4] = umin; }
            }
        } else {
            freeM |= 1ull << r;
        }
    }

    // ---- Dijkstra shortest augmenting path for collided rows ----
    while (freeM) {
        int r = (int)__builtin_ctzll(freeM);
        freeM &= freeM - 1;

        int used = used_inv;
#pragma unroll
        for (int s = 0; s < 5; s++) minv[s] = CINF;

        float rv[5];
        LOAD_ROW(r, rv);
        // u for the start row: min over columns of (c - v); v <= 0 so this is
        // >= raw row min (tighter) and still feasible. Floor-quantized.
        unsigned kb0 = 0xFFFFFFFFu;
#pragma unroll
        for (int s = 0; s < 5; s++)
            if (!((used_inv >> s) & 1))
                { unsigned kk = enc_key(rv[s] - v[s], s * 64 + lane); kb0 = (kk < kb0) ? kk : kb0; }
        float u_cur = dec_key(wave_min_u32(kb0));
        float u_i0 = u_cur;
        int j0 = 0;

        for (int guard = 0; guard < NN + 4; guard++) {
            if (j0 > 0) {
                int c0 = j0 - 1;
                if (lane == (c0 & 63)) used |= 1 << (c0 >> 6);
            }
            unsigned kbest = 0xFFFFFFFFu;
#pragma unroll
            for (int s = 0; s < 5; s++) {
                int c = s * 64 + lane;
                bool skip = (used >> s) & 1;
                float cur = rv[s] - u_i0 - v[s];
                bool lt = !skip && (cur < minv[s]);
                minv[s] = lt ? cur : minv[s];
                way[s]  = lt ? j0 : way[s];
                unsigned kk = skip ? 0xFFFFFFFFu : enc_key(minv[s], c);
                kbest = (kk < kbest) ? kk : kbest;
            }
            unsigned kmin = wave_min_u32(kbest);
            float delta = dec_key(kmin);
            int jb = (int)(kmin & 0x1FFu);

            int sl = jb >> 6, ow = jb & 63;
            int pj = rdlane_i(sel5i(pc, sl), ow);
            float uj = rdlane_f(sel5f(uc, sl), ow);

            float rvn[5];
            if (pj > 0) LOAD_ROW(pj - 1, rvn);   // prefetch next row

            u_cur += delta;
#pragma unroll
            for (int s = 0; s < 5; s++) {
                bool us = (used >> s) & 1;
                v[s]    = us ? v[s] - delta  : v[s];     // v decreases on ASSIGNED cols only
                uc[s]   = us ? uc[s] + delta : uc[s];
                minv[s] = us ? minv[s]       : minv[s] - delta;
            }

            j0 = jb + 1;
            if (pj == 0) break;                  // free column: v[jb] untouched (stays 0)
            u_i0 = uj;
#pragma unroll
            for (int s = 0; s < 5; s++) rv[s] = rvn[s];
        }

        // augment along way-chain
        int j = j0;
        int safety = 0;
        while (j && safety++ < NN + 4) {
            int co = j - 1, ow = co & 63, sl = co >> 6;
            int j1 = rdlane_i(sel5i(way, sl), ow);
            int pnew; float unew;
            if (j1 == 0) { pnew = r + 1; unew = u_cur; }
            else {
                int co1 = j1 - 1, ow1 = co1 & 63, sl1 = co1 >> 6;
                pnew = rdlane_i(sel5i(pc, sl1), ow1);
                unew = rdlane_f(sel5f(uc, sl1), ow1);
            }
            if (lane == ow) {
                if      (sl == 0) { pc[0] = pnew; uc[0] = unew; }
                else if (sl == 1) { pc[1] = pnew; uc[1] = unew; }
                else if (sl == 2) { pc[2] = pnew; uc[2] = unew; }
                else if (sl == 3) { pc[3] = pnew; uc[3] = unew; }
                else              { pc[4] = pnew; uc[4] = unew; }
            }
            j = j1;
        }
    }

#pragma unroll
    for (int s = 0; s < 5; s++) {
        int c = s * 64 + lane;
        if (c < NN) g_match[b * NN + c] = pc[s] - 1;
    }
#undef LOAD_ROW
}

// ---- losses (pair + obj BCE + aux + cls log-softmax) with fused finalize ----

__device__ __forceinline__ double bce_term(float x, float t) {
    return (double)(fmaxf(x, 0.0f) - x * t + log1pf(expf(-fabsf(x))));
}

__global__ __launch_bounds__(256) void losses_kernel(
    const float* __restrict__ pred, const float* __restrict__ tgt,
    const float* __restrict__ auxp, const float* __restrict__ obj,
    const float* __restrict__ auxobj, const float* __restrict__ logits,
    const int* __restrict__ label, float* __restrict__ out)
{
    const int tid = threadIdx.x;
    const int blk = blockIdx.x;
    __shared__ float  smax[256];
    __shared__ double ssum[256];

    if (blk < PAIR_BLOCKS) {
        int idx = blk * 256 + tid;
        double sb = 0.0, sg = 0.0, sab = 0.0, sag = 0.0, nb = 0.0, so = 0.0, sao = 0.0;
        if (idx < BN * NN) {
            int t = g_match[idx];
            float tv = (t >= 0) ? 1.0f : 0.0f;
            so = bce_term(obj[idx], tv);
            for (int l = 0; l < LAUX; l++)
                sao += bce_term(auxobj[l * BN * NN + idx], tv);
            if (t >= 0) {
                int b = idx / NN;
                float4 p = ((const float4*)pred)[idx];
                float4 tg = ((const float4*)tgt)[b * MM + t];
                float tx0 = tg.x - tg.z * 0.5f, ty0 = tg.y - tg.w * 0.5f;
                float tx1 = tg.x + tg.z * 0.5f, ty1 = tg.y + tg.w * 0.5f;
                {
                    float l1 = fabsf(p.x - tg.x) + fabsf(p.y - tg.y) + fabsf(p.z - tg.z) + fabsf(p.w - tg.w);
                    float gi = giou_box(p.x - p.z * 0.5f, p.y - p.w * 0.5f, p.x + p.z * 0.5f, p.y + p.w * 0.5f,
                                        tx0, ty0, tx1, ty1);
                    sb = (double)l1;
                    sg = (double)(1.0f - gi);
                    nb = 1.0;
                }
                for (int l = 0; l < LAUX; l++) {
                    float4 a = ((const float4*)auxp)[(size_t)l * BN * NN + idx];
                    float l1 = fabsf(a.x - tg.x) + fabsf(a.y - tg.y) + fabsf(a.z - tg.z) + fabsf(a.w - tg.w);
                    float gi = giou_box(a.x - a.z * 0.5f, a.y - a.w * 0.5f, a.x + a.z * 0.5f, a.y + a.w * 0.5f,
                                        tx0, ty0, tx1, ty1);
                    sab += (double)l1;
                    sag += (double)(1.0f - gi);
                }
            }
        }
        for (int off = 32; off; off >>= 1) {
            sb  += __shfl_down(sb, off, 64);
            sg  += __shfl_down(sg, off, 64);
            sab += __shfl_down(sab, off, 64);
            sag += __shfl_down(sag, off, 64);
            nb  += __shfl_down(nb, off, 64);
            so  += __shfl_down(so, off, 64);
            sao += __shfl_down(sao, off, 64);
        }
        if ((tid & 63) == 0) {
            atomicAdd(&g_acc[ACC_BBOX], sb);
            atomicAdd(&g_acc[ACC_GIOU], sg);
            atomicAdd(&g_acc[ACC_ABBOX], sab);
            atomicAdd(&g_acc[ACC_AGIOU], sag);
            atomicAdd(&g_acc[ACC_NB], nb);
            atomicAdd(&g_acc[ACC_OBJ], so);
            atomicAdd(&g_acc[ACC_AOBJ], sao);
        }
    } else {
        const int b = blk - PAIR_BLOCKS;
        const float* row = logits + (size_t)b * CNUM;
        float mx = -1e30f;
        for (int c = tid; c < CNUM; c += 256) mx = fmaxf(mx, row[c]);
        smax[tid] = mx;
        __syncthreads();
        for (int s = 128; s; s >>= 1) {
            if (tid < s) smax[tid] = fmaxf(smax[tid], smax[tid + s]);
            __syncthreads();
        }
        mx = smax[0];
        double s = 0.0;
        for (int c = tid; c < CNUM; c += 256) s += exp((double)(row[c] - mx));
        ssum[tid] = s;
        __syncthreads();
        for (int st = 128; st; st >>= 1) {
            if (tid < st) ssum[tid] += ssum[tid + st];
            __syncthreads();
        }
        if (tid == 0) {
            double lse = log(ssum[0]) + (double)mx;
            atomicAdd(&g_acc[ACC_CLS], lse - (double)row[label[b]]);
        }
    }

    // Last block finalizes; accumulators read back through the same coherent
    // RMW channel the writers used.
    __syncthreads();
    if (tid == 0) {
        __threadfence();
        int done = atomicAdd(&g_done, 1);
        if (done == GRID_L - 1) {
            __threadfence();
            double a[8];
#pragma unroll
            for (int i = 0; i < 8; i++) a[i] = atomicAdd(&g_acc[i], 0.0);
            double nb = a[ACC_NB] < 1.0 ? 1.0 : a[ACC_NB];
            double cls  = a[ACC_CLS] / (double)BN;
            double bbox = a[ACC_BBOX] / nb;
            double giou = a[ACC_GIOU] / nb;
            double objl = a[ACC_OBJ] / (double)(BN * NN);
            double ab   = a[ACC_ABBOX] / nb;
            double ag   = a[ACC_AGIOU] / nb;
            double ao   = a[ACC_AOBJ] / (double)(BN * NN);
            double aux  = (5.0 * ab + 2.0 * ag + 1.0 * ao) * 0.5 / (double)LAUX;
            out[0] = (float)(cls + 5.0 * bbox + 2.0 * giou + objl + aux);
        }
    }
}

extern "C" void kernel_launch(void* const* d_in, const int* in_sizes, int n_in,
                              void* d_out, int out_size, void* d_ws, size_t ws_size,
                              hipStream_t stream) {
    const float* cls_logits = (const float*)d_in[0];
    const int* label = (const int*)d_in[1];
    const float* pred_bboxes = (const float*)d_in[2];
    const float* obj_scores = (const float*)d_in[3];
    const float* target_bboxes = (const float*)d_in[4];
    const float* bbox_mask = (const float*)d_in[5];
    const float* aux_pred = (const float*)d_in[6];
    const float* aux_obj = (const float*)d_in[7];
    float* out = (float*)d_out;

    hung_kernel<<<BN, 128, 0, stream>>>(pred_bboxes, target_bboxes, bbox_mask);
    losses_kernel<<<GRID_L, 256, 0, stream>>>(pred_bboxes, target_bboxes, aux_pred,
                                              obj_scores, aux_obj, cls_logits, label, out);
}

// Round 8
// 292.271 us; speedup vs baseline: 1.1494x; 1.1494x over previous
//
#include <hip/hip_runtime.h>
#include <math.h>

// Problem constants (fixed by setup_inputs)
#define BN   32      // batch
#define NN   300     // num preds (columns of the transposed k x 300 problem)
#define MM   60      // max targets (rows)
#define LAUX 5       // aux layers
#define CNUM 1000    // classes

#define LC_ROWS 54   // cost rows staged in LDS; rows 54..59 spill to global
#define CINF 3.0e38f

// Accumulator slots
#define ACC_CLS   0
#define ACC_OBJ   1
#define ACC_AOBJ  2
#define ACC_BBOX  3
#define ACC_GIOU  4
#define ACC_ABBOX 5
#define ACC_AGIOU 6
#define ACC_NB    7

#define PAIR_BLOCKS ((BN * NN + 255) / 256)   // 38
#define GRID_L (PAIR_BLOCKS + BN)             // 70

__device__ int    g_match[BN * NN];
__device__ double g_acc[8];
__device__ int    g_done;
__device__ float  g_spill[BN][(MM - LC_ROWS) * NN + 32];   // rows 54..59 per batch

__device__ __forceinline__ float giou_box(float ax0, float ay0, float ax1, float ay1,
                                          float bx0, float by0, float bx1, float by1) {
    const float EPS = 1e-7f;
    float area_a = (ax1 - ax0) * (ay1 - ay0);
    float area_b = (bx1 - bx0) * (by1 - by0);
    float ltx = fmaxf(ax0, bx0), lty = fmaxf(ay0, by0);
    float rbx = fminf(ax1, bx1), rby = fminf(ay1, by1);
    float w = fmaxf(rbx - ltx, 0.0f), h = fmaxf(rby - lty, 0.0f);
    float inter = w * h;
    float uni = area_a + area_b - inter;
    float iou = inter / (uni + EPS);
    float ex0 = fminf(ax0, bx0), ey0 = fminf(ay0, by0);
    float ex1 = fmaxf(ax1, bx1), ey1 = fmaxf(ay1, by1);
    float ew = fmaxf(ex1 - ex0, 0.0f), eh = fmaxf(ey1 - ey0, 0.0f);
    float enc = ew * eh;
    return iou - (enc - uni) / (enc + EPS);
}

__device__ __forceinline__ float cost_pt(float4 p, float4 t) {
    float l1 = fabsf(p.x - t.x) + fabsf(p.y - t.y) + fabsf(p.z - t.z) + fabsf(p.w - t.w);
    float gi = giou_box(p.x - p.z * 0.5f, p.y - p.w * 0.5f, p.x + p.z * 0.5f, p.y + p.w * 0.5f,
                        t.x - t.z * 0.5f, t.y - t.w * 0.5f, t.x + t.z * 0.5f, t.y + t.w * 0.5f);
    return 5.0f * l1 - 2.0f * gi;
}

// ---- packed-key wave reductions --------------------------------------------
// key = order-preserving f32 (upper 23 bits) | column (low 9 bits); floor quant.
__device__ __forceinline__ unsigned enc_key(float x, int col) {
    unsigned u = __float_as_uint(x);
    unsigned e = (u & 0x80000000u) ? ~u : (u | 0x80000000u);
    return (e & 0xFFFFFE00u) | (unsigned)col;
}
__device__ __forceinline__ float dec_key(unsigned kk) {
    unsigned e = kk & 0xFFFFFE00u;
    unsigned u = (e & 0x80000000u) ? (e & 0x7FFFFFFFu) : ~e;
    return __uint_as_float(u);
}

__device__ __forceinline__ unsigned wave_min_u32(unsigned k) {
#define WSTEP(C) { unsigned t = (unsigned)__builtin_amdgcn_update_dpp((int)k, (int)k, (C), 0xF, 0xF, false); \
                   k = (t < k) ? t : k; }
    WSTEP(0x111) WSTEP(0x112) WSTEP(0x114) WSTEP(0x118) WSTEP(0x142) WSTEP(0x143)
#undef WSTEP
    return (unsigned)__builtin_amdgcn_readlane((int)k, 63);
}

// (min, second-min) over the wave; per-lane inputs a<=b over distinct columns.
// shr/bcast merge tree combines disjoint lane ranges -> exact distinct top-2.
__device__ __forceinline__ void wave_min2_u32(unsigned a, unsigned b,
                                              unsigned* m1, unsigned* m2) {
#define PSTEP(C) { \
    unsigned oa = (unsigned)__builtin_amdgcn_update_dpp(-1, (int)a, (C), 0xF, 0xF, false); \
    unsigned ob = (unsigned)__builtin_amdgcn_update_dpp(-1, (int)b, (C), 0xF, 0xF, false); \
    unsigned mn = (a < oa) ? a : oa; \
    unsigned mx = (a < oa) ? oa : a; \
    unsigned nb = (b < ob) ? b : ob; \
    a = mn; b = (mx < nb) ? mx : nb; }
    PSTEP(0x111) PSTEP(0x112) PSTEP(0x114) PSTEP(0x118) PSTEP(0x142) PSTEP(0x143)
#undef PSTEP
    *m1 = (unsigned)__builtin_amdgcn_readlane((int)a, 63);
    *m2 = (unsigned)__builtin_amdgcn_readlane((int)b, 63);
}

__device__ __forceinline__ int sel5i(const int* a, int s) {
    int r = a[0];
    r = (s == 1) ? a[1] : r;
    r = (s == 2) ? a[2] : r;
    r = (s == 3) ? a[3] : r;
    r = (s == 4) ? a[4] : r;
    return r;
}
__device__ __forceinline__ float sel5f(const float* a, int s) {
    float r = a[0];
    r = (s == 1) ? a[1] : r;
    r = (s == 2) ? a[2] : r;
    r = (s == 3) ? a[3] : r;
    r = (s == 4) ? a[4] : r;
    return r;
}
__device__ __forceinline__ int rdlane_i(int x, int l) { return __builtin_amdgcn_readlane(x, l); }
__device__ __forceinline__ float rdlane_f(float x, int l) {
    return __uint_as_float((unsigned)__builtin_amdgcn_readlane(__float_as_int(x), l));
}

// ---- fused cost + LAPJV (aug-row-reduction + Dijkstra) ---------------------
// Invariant (rectangular LAP): v <= 0 everywhere, v == 0 on unassigned columns.
// Phase 2 decreases v only on columns that end the step assigned; Dijkstra
// decreases v only on 'used' (assigned) columns. Exact rc1/rc2 readback keeps
// duals feasible to f32 exactness (argmin selection quantized; slack ~1 ulp/2^14).
__global__ __launch_bounds__(128) void hung_kernel(const float* __restrict__ pred,
                                                   const float* __restrict__ tgt,
                                                   const float* __restrict__ mask) {
    const int b = blockIdx.x;
    const int tid = threadIdx.x;
    const int lane = tid & 63;
    const int wid = tid >> 6;

    __shared__ float lc[LC_ROWS * NN + 32];

    if (b == 0 && tid == 0) {
        __hip_atomic_store(&g_done, 0, __ATOMIC_RELAXED, __HIP_MEMORY_SCOPE_AGENT);
#pragma unroll
        for (int i = 0; i < 8; i++)
            __hip_atomic_store(&g_acc[i], 0.0, __ATOMIC_RELAXED, __HIP_MEMORY_SCOPE_AGENT);
    }

    float mval = (lane < MM) ? mask[b * MM + lane] : 0.0f;
    int k = __popcll(__ballot(mval > 0.5f));

    float4 pb[5];
#pragma unroll
    for (int s = 0; s < 5; s++) {
        int c = s * 64 + lane;
        pb[s] = (c < NN) ? ((const float4*)pred)[b * NN + c]
                         : make_float4(0.f, 0.f, 0.f, 0.f);
    }

    // cost tile: rows 0..53 -> LDS, rows 54..k-1 -> global spill (both waves)
    float* spill = g_spill[b];
    int kl = (k < LC_ROWS) ? k : LC_ROWS;
    for (int r = wid; r < kl; r += 2) {
        float4 tb = ((const float4*)tgt)[b * MM + r];
#pragma unroll
        for (int s = 0; s < 5; s++) {
            int c = s * 64 + lane;
            if (c < NN) lc[r * NN + c] = cost_pt(pb[s], tb);
        }
    }
    for (int r = LC_ROWS + wid; r < k; r += 2) {
        float4 tb = ((const float4*)tgt)[b * MM + r];
#pragma unroll
        for (int s = 0; s < 5; s++) {
            int c = s * 64 + lane;
            if (c < NN) spill[(r - LC_ROWS) * NN + c] = cost_pt(pb[s], tb);
        }
    }
    __syncthreads();        // drains vmcnt: spill stores visible to wave0's loads
    if (wid == 1) return;

#define ROW_PTR(R) (((R) < LC_ROWS) ? (const float*)(lc + (R) * NN) \
                                    : (const float*)(spill + ((R) - LC_ROWS) * NN))

    int used_inv = 0;
#pragma unroll
    for (int s = 0; s < 5; s++)
        if (s * 64 + lane >= NN) used_inv |= 1 << s;

    float v[5], uc[5], minv[5];
    int pc[5], way[5];
#pragma unroll
    for (int s = 0; s < 5; s++) { v[s] = 0.0f; uc[s] = 0.0f; pc[s] = 0; way[s] = 0; }

#define ASSIGN(J, ROW1, U) do { int _j = (J); if (lane == (_j & 63)) {          \
        int _sl = _j >> 6; float _u = (U); int _rw = (ROW1);                    \
        if      (_sl == 0) { pc[0] = _rw; uc[0] = _u; }                         \
        else if (_sl == 1) { pc[1] = _rw; uc[1] = _u; }                         \
        else if (_sl == 2) { pc[2] = _rw; uc[2] = _u; }                         \
        else if (_sl == 3) { pc[3] = _rw; uc[3] = _u; }                         \
        else               { pc[4] = _rw; uc[4] = _u; } } } while (0)
#define V_SUB(J, D) do { int _j = (J); if (lane == (_j & 63)) {                 \
        int _sl = _j >> 6; float _d = (D);                                      \
        if      (_sl == 0) v[0] -= _d; else if (_sl == 1) v[1] -= _d;           \
        else if (_sl == 2) v[2] -= _d; else if (_sl == 3) v[3] -= _d;           \
        else v[4] -= _d; } } while (0)

    // ---- LAPJV augmenting row reduction: 2 passes, step-capped ----
    unsigned long long pend = (k >= 64) ? ~0ull : ((1ull << k) - 1ull);
    int steps = 0;
    const int cap = 8 * k + 64;
    for (int pass = 0; pass < 2; pass++) {
        unsigned long long cur = pend;
        pend = 0ull;
        int i1 = -1;
        while (true) {
            if (i1 < 0) {
                if (!cur) break;
                i1 = (int)__builtin_ctzll(cur);
                cur &= cur - 1;
            }
            if (steps >= cap) { pend |= (1ull << i1) | cur; break; }
            steps++;
            const float* rowp = ROW_PTR(i1);
            float rc[5];
            unsigned kb = 0xFFFFFFFFu, ks = 0xFFFFFFFFu;
#pragma unroll
            for (int s = 0; s < 5; s++) {
                rc[s] = rowp[s * 64 + lane] - v[s];
                if (!((used_inv >> s) & 1)) {
                    unsigned kk = enc_key(rc[s], s * 64 + lane);
                    if (kk < kb) { ks = kb; kb = kk; }
                    else if (kk < ks) ks = kk;
                }
            }
            unsigned m1k, m2k;
            wave_min2_u32(kb, ks, &m1k, &m2k);
            int j1 = (int)(m1k & 0x1FFu);
            int j2 = (int)(m2k & 0x1FFu);
            bool havem2 = (m2k != 0xFFFFFFFFu);
            float rc1 = rdlane_f(sel5f(rc, j1 >> 6), j1 & 63);
            float rc2 = havem2 ? rdlane_f(sel5f(rc, j2 >> 6), j2 & 63) : CINF;
            int i0 = rdlane_i(sel5i(pc, j1 >> 6), j1 & 63);
            bool strict = havem2 && (rc1 < rc2);
            if (strict) {
                V_SUB(j1, rc2 - rc1);                 // j1 ends assigned; invariant ok
                ASSIGN(j1, i1 + 1, rc2);              // uc = c - v_new (exact)
                i1 = (i0 > 0) ? (i0 - 1) : -1;        // chain displaced row
            } else if (i0 == 0) {
                ASSIGN(j1, i1 + 1, rc1);
                i1 = -1;
            } else if (havem2) {
                int i0b = rdlane_i(sel5i(pc, j2 >> 6), j2 & 63);
                ASSIGN(j2, i1 + 1, rc2);              // tie: rc2 == rc1, v unchanged
                if (i0b > 0) pend |= 1ull << (i0b - 1);  // defer displaced
                i1 = -1;
            } else {
                pend |= 1ull << i1;                   // nothing safe to do; defer
                i1 = -1;
            }
        }
    }

    // ---- Dijkstra shortest augmenting path for leftover rows ----
    unsigned long long freeM = pend;
    while (freeM) {
        int r = (int)__builtin_ctzll(freeM);
        freeM &= freeM - 1;

        int used = used_inv;
#pragma unroll
        for (int s = 0; s < 5; s++) minv[s] = CINF;

        const float* rp0 = ROW_PTR(r);
        unsigned kb0 = 0xFFFFFFFFu;
#pragma unroll
        for (int s = 0; s < 5; s++)
            if (!((used_inv >> s) & 1)) {
                unsigned kk = enc_key(rp0[s * 64 + lane] - v[s], s * 64 + lane);
                kb0 = (kk < kb0) ? kk : kb0;
            }
        float u_cur = dec_key(wave_min_u32(kb0));
        float u_i0 = u_cur;
        int i0 = r + 1;
        int j0 = 0;

        for (int guard = 0; guard < NN + 4; guard++) {
            if (j0 > 0) {
                int c0 = j0 - 1;
                if (lane == (c0 & 63)) used |= 1 << (c0 >> 6);
            }
            const float* rowp = ROW_PTR(i0 - 1);
            unsigned kbest = 0xFFFFFFFFu;
#pragma unroll
            for (int s = 0; s < 5; s++) {
                int c = s * 64 + lane;
                bool skip = (used >> s) & 1;
                float cur = rowp[c] - u_i0 - v[s];
                bool lt = !skip && (cur < minv[s]);
                minv[s] = lt ? cur : minv[s];
                way[s]  = lt ? j0 : way[s];
                unsigned kk = skip ? 0xFFFFFFFFu : enc_key(minv[s], c);
                kbest = (kk < kbest) ? kk : kbest;
            }
            unsigned kmin = wave_min_u32(kbest);
            float delta = dec_key(kmin);
            int jb = (int)(kmin & 0x1FFu);

            int sl = jb >> 6, ow = jb & 63;
            int pj = rdlane_i(sel5i(pc, sl), ow);
            float uj = rdlane_f(sel5f(uc, sl), ow);

            u_cur += delta;
#pragma unroll
            for (int s = 0; s < 5; s++) {
                bool us = (used >> s) & 1;
                v[s]    = us ? v[s] - delta  : v[s];   // assigned cols only
                uc[s]   = us ? uc[s] + delta : uc[s];
                minv[s] = us ? minv[s]       : minv[s] - delta;
            }

            j0 = jb + 1;
            if (pj == 0) break;                        // free col: v[jb] stays 0
            i0 = pj;
            u_i0 = uj;
        }

        // augment along way-chain
        int j = j0;
        int safety = 0;
        while (j && safety++ < NN + 4) {
            int co = j - 1, ow = co & 63, sl = co >> 6;
            int j1 = rdlane_i(sel5i(way, sl), ow);
            int pnew; float unew;
            if (j1 == 0) { pnew = r + 1; unew = u_cur; }
            else {
                int co1 = j1 - 1, ow1 = co1 & 63, sl1 = co1 >> 6;
                pnew = rdlane_i(sel5i(pc, sl1), ow1);
                unew = rdlane_f(sel5f(uc, sl1), ow1);
            }
            ASSIGN(co, pnew, unew);
            j = j1;
        }
    }

#pragma unroll
    for (int s = 0; s < 5; s++) {
        int c = s * 64 + lane;
        if (c < NN) g_match[b * NN + c] = pc[s] - 1;
    }
#undef ROW_PTR
#undef ASSIGN
#undef V_SUB
}

// ---- losses (pair + obj BCE + aux + cls log-softmax) with fused finalize ----

__device__ __forceinline__ double bce_term(float x, float t) {
    return (double)(fmaxf(x, 0.0f) - x * t + log1pf(expf(-fabsf(x))));
}

__global__ __launch_bounds__(256) void losses_kernel(
    const float* __restrict__ pred, const float* __restrict__ tgt,
    const float* __restrict__ auxp, const float* __restrict__ obj,
    const float* __restrict__ auxobj, const float* __restrict__ logits,
    const int* __restrict__ label, float* __restrict__ out)
{
    const int tid = threadIdx.x;
    const int blk = blockIdx.x;
    __shared__ float  smax[256];
    __shared__ double ssum[256];

    if (blk < PAIR_BLOCKS) {
        int idx = blk * 256 + tid;
        double sb = 0.0, sg = 0.0, sab = 0.0, sag = 0.0, nb = 0.0, so = 0.0, sao = 0.0;
        if (idx < BN * NN) {
            int t = g_match[idx];
            float tv = (t >= 0) ? 1.0f : 0.0f;
            so = bce_term(obj[idx], tv);
            for (int l = 0; l < LAUX; l++)
                sao += bce_term(auxobj[l * BN * NN + idx], tv);
            if (t >= 0) {
                int b = idx / NN;
                float4 p = ((const float4*)pred)[idx];
                float4 tg = ((const float4*)tgt)[b * MM + t];
                float tx0 = tg.x - tg.z * 0.5f, ty0 = tg.y - tg.w * 0.5f;
                float tx1 = tg.x + tg.z * 0.5f, ty1 = tg.y + tg.w * 0.5f;
                {
                    float l1 = fabsf(p.x - tg.x) + fabsf(p.y - tg.y) + fabsf(p.z - tg.z) + fabsf(p.w - tg.w);
                    float gi = giou_box(p.x - p.z * 0.5f, p.y - p.w * 0.5f, p.x + p.z * 0.5f, p.y + p.w * 0.5f,
                                        tx0, ty0, tx1, ty1);
                    sb = (double)l1;
                    sg = (double)(1.0f - gi);
                    nb = 1.0;
                }
                for (int l = 0; l < LAUX; l++) {
                    float4 a = ((const float4*)auxp)[(size_t)l * BN * NN + idx];
                    float l1 = fabsf(a.x - tg.x) + fabsf(a.y - tg.y) + fabsf(a.z - tg.z) + fabsf(a.w - tg.w);
                    float gi = giou_box(a.x - a.z * 0.5f, a.y - a.w * 0.5f, a.x + a.z * 0.5f, a.y + a.w * 0.5f,
                                        tx0, ty0, tx1, ty1);
                    sab += (double)l1;
                    sag += (double)(1.0f - gi);
                }
            }
        }
        for (int off = 32; off; off >>= 1) {
            sb  += __shfl_down(sb, off, 64);
            sg  += __shfl_down(sg, off, 64);
            sab += __shfl_down(sab, off, 64);
            sag += __shfl_down(sag, off, 64);
            nb  += __shfl_down(nb, off, 64);
            so  += __shfl_down(so, off, 64);
            sao += __shfl_down(sao, off, 64);
        }
        if ((tid & 63) == 0) {
            atomicAdd(&g_acc[ACC_BBOX], sb);
            atomicAdd(&g_acc[ACC_GIOU], sg);
            atomicAdd(&g_acc[ACC_ABBOX], sab);
            atomicAdd(&g_acc[ACC_AGIOU], sag);
            atomicAdd(&g_acc[ACC_NB], nb);
            atomicAdd(&g_acc[ACC_OBJ], so);
            atomicAdd(&g_acc[ACC_AOBJ], sao);
        }
    } else {
        const int b = blk - PAIR_BLOCKS;
        const float* row = logits + (size_t)b * CNUM;
        float mx = -1e30f;
        for (int c = tid; c < CNUM; c += 256) mx = fmaxf(mx, row[c]);
        smax[tid] = mx;
        __syncthreads();
        for (int s = 128; s; s >>= 1) {
            if (tid < s) smax[tid] = fmaxf(smax[tid], smax[tid + s]);
            __syncthreads();
        }
        mx = smax[0];
        double s = 0.0;
        for (int c = tid; c < CNUM; c += 256) s += exp((double)(row[c] - mx));
        ssum[tid] = s;
        __syncthreads();
        for (int st = 128; st; st >>= 1) {
            if (tid < st) ssum[tid] += ssum[tid + st];
            __syncthreads();
        }
        if (tid == 0) {
            double lse = log(ssum[0]) + (double)mx;
            atomicAdd(&g_acc[ACC_CLS], lse - (double)row[label[b]]);
        }
    }

    __syncthreads();
    if (tid == 0) {
        __threadfence();
        int done = atomicAdd(&g_done, 1);
        if (done == GRID_L - 1) {
            __threadfence();
            double a[8];
#pragma unroll
            for (int i = 0; i < 8; i++) a[i] = atomicAdd(&g_acc[i], 0.0);
            double nb = a[ACC_NB] < 1.0 ? 1.0 : a[ACC_NB];
            double cls  = a[ACC_CLS] / (double)BN;
            double bbox = a[ACC_BBOX] / nb;
            double giou = a[ACC_GIOU] / nb;
            double objl = a[ACC_OBJ] / (double)(BN * NN);
            double ab   = a[ACC_ABBOX] / nb;
            double ag   = a[ACC_AGIOU] / nb;
            double ao   = a[ACC_AOBJ] / (double)(BN * NN);
            double aux  = (5.0 * ab + 2.0 * ag + 1.0 * ao) * 0.5 / (double)LAUX;
            out[0] = (float)(cls + 5.0 * bbox + 2.0 * giou + objl + aux);
        }
    }
}

extern "C" void kernel_launch(void* const* d_in, const int* in_sizes, int n_in,
                              void* d_out, int out_size, void* d_ws, size_t ws_size,
                              hipStream_t stream) {
    const float* cls_logits = (const float*)d_in[0];
    const int* label = (const int*)d_in[1];
    const float* pred_bboxes = (const float*)d_in[2];
    const float* obj_scores = (const float*)d_in[3];
    const float* target_bboxes = (const float*)d_in[4];
    const float* bbox_mask = (const float*)d_in[5];
    const float* aux_pred = (const float*)d_in[6];
    const float* aux_obj = (const float*)d_in[7];
    float* out = (float*)d_out;

    hung_kernel<<<BN, 128, 0, stream>>>(pred_bboxes, target_bboxes, bbox_mask);
    losses_kernel<<<GRID_L, 256, 0, stream>>>(pred_bboxes, target_bboxes, aux_pred,
                                              obj_scores, aux_obj, cls_logits, label, out);
}